// Round 4
// baseline (200.667 us; speedup 1.0000x reference)
//
#include <hip/hip_runtime.h>

// AffineLayer2d: 256 3x3 expm -> affine grid -> bilinear sample.
// x[8,3,224,224] f32, ksamp[6,8,32] f32, rf[6] f32 -> out[8,32,3,224,224] f32.
//
// R1: scattered-VMEM (TA/TD) bound -> R2 NHWC-pad4 reformat, float4 corner
// gathers: sample 120->~43us. R3/R4: 4 px/thread (VMEM insts/px 7->4.75,
// dwordx4 coalesced stores, 4x fewer waves) + nontemporal output stores so
// the 154MB out stream doesn't evict the 25.7MB L2-resident xi.
// (R3 failed to compile: __builtin_nontemporal_store needs a clang
// ext_vector_type pointer, not HIP's float4 class -> fixed with fvec4.)

#define PI_F 3.14159265358979323846f

typedef __attribute__((ext_vector_type(4))) float fvec4;  // clang-native float4

constexpr int N_ = 8, C_ = 3, H_ = 224, W_ = 224, S_ = 32;
constexpr int HW_ = H_ * W_;              // 50176
constexpr int B_ = N_ * S_;               // 256 transforms
constexpr int BLOCKS_PER_IMG = HW_ / 256; // 196 (prep grid)
constexpr int QUADS_ = HW_ / 4;           // 12544
constexpr int QBLOCKS_PER_IMG = QUADS_ / 256; // 49 (sample grid, exact)

constexpr size_t THETA_OFF = 0;
constexpr size_t XI_OFF    = 8192;        // 16B-aligned, 25.7 MB

// ---------------- Stage 1: theta = expm(M)[:, :2, :] ----------------
__device__ void compute_theta(const float* __restrict__ ksamp,
                              const float* __restrict__ rf,
                              float* __restrict__ theta) {
    int t = threadIdx.x;  // 256 threads = 256 transforms
    int n = t / S_, s = t % S_;

    float kk[6];
#pragma unroll
    for (int j = 0; j < 6; ++j)
        kk[j] = ksamp[j * (N_ * S_) + n * S_ + s] * 2.f - 1.f;

    float c2 = fminf(fmaxf(rf[2], -PI_F), PI_F);
    float a = kk[0] * rf[0];
    float b = kk[1] * rf[1];
    float r = kk[2] * c2;
    float d = kk[3] * rf[3];
    float e = kk[4] * rf[4];
    float f = kk[5] * rf[5];

    float A[9] = { d,     f - r, a,
                   f + r, e,     b,
                   0.f,   0.f,   0.f };

#pragma unroll
    for (int i = 0; i < 9; ++i) A[i] *= (1.f / 64.f);

    float out[9] = {1,0,0, 0,1,0, 0,0,1};
#pragma unroll
    for (int i = 0; i < 9; ++i) out[i] += A[i];

    float term[9];
#pragma unroll
    for (int i = 0; i < 9; ++i) term[i] = A[i];

#pragma unroll
    for (int it = 2; it <= 12; ++it) {
        float inv = 1.f / (float)it;
        float nt[9];
#pragma unroll
        for (int rr = 0; rr < 3; ++rr)
#pragma unroll
            for (int cc = 0; cc < 3; ++cc)
                nt[rr*3+cc] = (term[rr*3+0]*A[0*3+cc] +
                               term[rr*3+1]*A[1*3+cc] +
                               term[rr*3+2]*A[2*3+cc]) * inv;
#pragma unroll
        for (int i = 0; i < 9; ++i) { term[i] = nt[i]; out[i] += nt[i]; }
    }
#pragma unroll
    for (int sq = 0; sq < 6; ++sq) {
        float nt[9];
#pragma unroll
        for (int rr = 0; rr < 3; ++rr)
#pragma unroll
            for (int cc = 0; cc < 3; ++cc)
                nt[rr*3+cc] = out[rr*3+0]*out[0*3+cc] +
                              out[rr*3+1]*out[1*3+cc] +
                              out[rr*3+2]*out[2*3+cc];
#pragma unroll
        for (int i = 0; i < 9; ++i) out[i] = nt[i];
    }

    theta[t*6+0] = out[0]; theta[t*6+1] = out[1]; theta[t*6+2] = out[2];
    theta[t*6+3] = out[3]; theta[t*6+4] = out[4]; theta[t*6+5] = out[5];
}

// NCHW -> NHWC(pad4). Loads 3 coalesced dword streams, stores coalesced dwordx4.
__global__ __launch_bounds__(256) void prep_kernel(const float* __restrict__ x,
                                                   const float* __restrict__ ksamp,
                                                   const float* __restrict__ rf,
                                                   float4* __restrict__ xi,
                                                   float* __restrict__ theta) {
    int idx = blockIdx.x * 256 + threadIdx.x;   // over N*HW
    int n = idx / HW_, p = idx - n * HW_;
    const float* base = x + n * (C_ * HW_) + p;
    float4 v;
    v.x = base[0];
    v.y = base[HW_];
    v.z = base[2 * HW_];
    v.w = 0.f;
    xi[idx] = v;

    if (blockIdx.x == 0) compute_theta(ksamp, rf, theta);
}

// ---------------- Stage 2: affine grid + bilinear sample, 4 px/thread ----------------
__global__ __launch_bounds__(256) void sample_kernel(const float4* __restrict__ xi,
                                                     const float* __restrict__ theta,
                                                     float* __restrict__ out) {
    int blk = blockIdx.x;
    int b   = blk / QBLOCKS_PER_IMG;                       // uniform per block
    int q   = (blk % QBLOCKS_PER_IMG) * 256 + threadIdx.x; // quad index
    int pix = q * 4;
    int h = pix / W_, w = pix - h * W_;                    // quad stays in one row
    int n = b / S_;

    const float* th = theta + b * 6;
    float t00 = th[0], t01 = th[1], t02 = th[2];
    float t10 = th[3], t11 = th[4], t12 = th[5];

    const float4* img = xi + n * HW_;

    float gy = fmaf((float)h, 2.f / (H_ - 1), -1.f);
    float cx = t01 * gy + t02;   // gridx = t00*gx + cx
    float cy = t11 * gy + t12;   // gridy = t10*gx + cy

    float vx[4], vy[4], vz[4];

#pragma unroll
    for (int j = 0; j < 4; ++j) {
        float gx = fmaf((float)(w + j), 2.f / (W_ - 1), -1.f);
        float ix = (fmaf(t00, gx, cx) + 1.f) * (0.5f * (W_ - 1));
        float iy = (fmaf(t10, gx, cy) + 1.f) * (0.5f * (H_ - 1));

        float x0f = floorf(ix), y0f = floorf(iy);
        float wx1 = ix - x0f, wx0 = 1.f - wx1;
        float wy1 = iy - y0f, wy0 = 1.f - wy1;

        int x0 = (int)x0f, y0 = (int)y0f;
        int x1 = x0 + 1,   y1 = y0 + 1;

        bool vx0 = (x0 >= 0) && (x0 <= W_ - 1);
        bool vx1b = (x1 >= 0) && (x1 <= W_ - 1);
        bool vy0 = (y0 >= 0) && (y0 <= H_ - 1);
        bool vy1b = (y1 >= 0) && (y1 <= H_ - 1);

        float w00 = (vy0  && vx0 ) ? wy0 * wx0 : 0.f;
        float w01 = (vy0  && vx1b) ? wy0 * wx1 : 0.f;
        float w10 = (vy1b && vx0 ) ? wy1 * wx0 : 0.f;
        float w11 = (vy1b && vx1b) ? wy1 * wx1 : 0.f;

        int x0c = min(max(x0, 0), W_ - 1), x1c = min(max(x1, 0), W_ - 1);
        int y0c = min(max(y0, 0), H_ - 1), y1c = min(max(y1, 0), H_ - 1);

        float4 p00 = img[y0c * W_ + x0c];
        float4 p01 = img[y0c * W_ + x1c];
        float4 p10 = img[y1c * W_ + x0c];
        float4 p11 = img[y1c * W_ + x1c];

        vx[j] = w00 * p00.x + w01 * p01.x + w10 * p10.x + w11 * p11.x;
        vy[j] = w00 * p00.y + w01 * p01.y + w10 * p10.y + w11 * p11.y;
        vz[j] = w00 * p00.z + w01 * p01.z + w10 * p10.z + w11 * p11.z;
    }

    float* ob = out + (size_t)b * (C_ * HW_) + pix;
    fvec4 sx = {vx[0], vx[1], vx[2], vx[3]};
    fvec4 sy = {vy[0], vy[1], vy[2], vy[3]};
    fvec4 sz = {vz[0], vz[1], vz[2], vz[3]};
    __builtin_nontemporal_store(sx, (fvec4*)(ob));
    __builtin_nontemporal_store(sy, (fvec4*)(ob + HW_));
    __builtin_nontemporal_store(sz, (fvec4*)(ob + 2 * (size_t)HW_));
}

extern "C" void kernel_launch(void* const* d_in, const int* in_sizes, int n_in,
                              void* d_out, int out_size, void* d_ws, size_t ws_size,
                              hipStream_t stream) {
    const float* x     = (const float*)d_in[0];
    const float* ksamp = (const float*)d_in[1];
    const float* rf    = (const float*)d_in[2];
    float* out   = (float*)d_out;
    float* theta = (float*)((char*)d_ws + THETA_OFF);
    float4* xi   = (float4*)((char*)d_ws + XI_OFF);

    prep_kernel<<<N_ * BLOCKS_PER_IMG, 256, 0, stream>>>(x, ksamp, rf, xi, theta);
    sample_kernel<<<B_ * QBLOCKS_PER_IMG, 256, 0, stream>>>(xi, theta, out);
}

// Round 5
// 173.216 us; speedup vs baseline: 1.1585x; 1.1585x over previous
//
#include <hip/hip_runtime.h>
#include <hip/hip_bf16.h>

// AffineLayer2d: 256 3x3 expm -> affine grid -> bilinear sample.
// x[8,3,224,224] f32, ksamp[6,8,32] f32, rf[6] f32 -> out[8,32,3,224,224] f32.
//
// R1: scattered-VMEM bound (12 scalar gathers). R2: NHWC-pad4 float4 corner
// gathers -> sample ~50us. R4: 4px/thread REGRESSED (VGPR/in-flight-load
// pressure; bound is TD cacheline throughput, not inst issue).
// R5: xi compressed to bf16x4 (8B/px): halves gather line traffic, whole
// image = 3.2MB (< 4MB per-XCD L2); x-adjacent corner pair = 16 contiguous
// bytes -> one pair-load per row. 1px/thread. NT scalar stores keep the
// 154MB out stream from evicting L2-resident xi.

#define PI_F 3.14159265358979323846f

typedef uint uvec4 __attribute__((ext_vector_type(4)));
typedef uint uvec2 __attribute__((ext_vector_type(2)));

constexpr int N_ = 8, C_ = 3, H_ = 224, W_ = 224, S_ = 32;
constexpr int HW_ = H_ * W_;              // 50176
constexpr int B_ = N_ * S_;               // 256 transforms
constexpr int BLOCKS_PER_IMG = HW_ / 256; // 196

constexpr size_t THETA_OFF = 0;
constexpr size_t XI_OFF    = 8192;        // bf16x4 image, 3.2 MB (+pad)

// bf16 pair unpack: u holds (lo16=bf16 a, hi16=bf16 b)
__device__ inline float bflo(uint u) { return __uint_as_float(u << 16); }
__device__ inline float bfhi(uint u) { return __uint_as_float(u & 0xffff0000u); }

// ---------------- Stage 1: theta = expm(M)[:, :2, :] ----------------
__device__ void compute_theta(const float* __restrict__ ksamp,
                              const float* __restrict__ rf,
                              float* __restrict__ theta) {
    int t = threadIdx.x;  // 256 threads = 256 transforms
    int n = t / S_, s = t % S_;

    float kk[6];
#pragma unroll
    for (int j = 0; j < 6; ++j)
        kk[j] = ksamp[j * (N_ * S_) + n * S_ + s] * 2.f - 1.f;

    float c2 = fminf(fmaxf(rf[2], -PI_F), PI_F);
    float a = kk[0] * rf[0];
    float b = kk[1] * rf[1];
    float r = kk[2] * c2;
    float d = kk[3] * rf[3];
    float e = kk[4] * rf[4];
    float f = kk[5] * rf[5];

    float A[9] = { d,     f - r, a,
                   f + r, e,     b,
                   0.f,   0.f,   0.f };

#pragma unroll
    for (int i = 0; i < 9; ++i) A[i] *= (1.f / 64.f);

    float out[9] = {1,0,0, 0,1,0, 0,0,1};
#pragma unroll
    for (int i = 0; i < 9; ++i) out[i] += A[i];

    float term[9];
#pragma unroll
    for (int i = 0; i < 9; ++i) term[i] = A[i];

#pragma unroll
    for (int it = 2; it <= 12; ++it) {
        float inv = 1.f / (float)it;
        float nt[9];
#pragma unroll
        for (int rr = 0; rr < 3; ++rr)
#pragma unroll
            for (int cc = 0; cc < 3; ++cc)
                nt[rr*3+cc] = (term[rr*3+0]*A[0*3+cc] +
                               term[rr*3+1]*A[1*3+cc] +
                               term[rr*3+2]*A[2*3+cc]) * inv;
#pragma unroll
        for (int i = 0; i < 9; ++i) { term[i] = nt[i]; out[i] += nt[i]; }
    }
#pragma unroll
    for (int sq = 0; sq < 6; ++sq) {
        float nt[9];
#pragma unroll
        for (int rr = 0; rr < 3; ++rr)
#pragma unroll
            for (int cc = 0; cc < 3; ++cc)
                nt[rr*3+cc] = out[rr*3+0]*out[0*3+cc] +
                              out[rr*3+1]*out[1*3+cc] +
                              out[rr*3+2]*out[2*3+cc];
#pragma unroll
        for (int i = 0; i < 9; ++i) out[i] = nt[i];
    }

    theta[t*6+0] = out[0]; theta[t*6+1] = out[1]; theta[t*6+2] = out[2];
    theta[t*6+3] = out[3]; theta[t*6+4] = out[4]; theta[t*6+5] = out[5];
}

// NCHW fp32 -> NHWC bf16x4 (8B/pixel). Coalesced reads + coalesced 8B stores.
__global__ __launch_bounds__(256) void prep_kernel(const float* __restrict__ x,
                                                   const float* __restrict__ ksamp,
                                                   const float* __restrict__ rf,
                                                   uvec2* __restrict__ xi,
                                                   float* __restrict__ theta) {
    int idx = blockIdx.x * 256 + threadIdx.x;   // over N*HW
    int n = idx / HW_, p = idx - n * HW_;
    const float* base = x + n * (C_ * HW_) + p;
    uint b0 = (uint)__bfloat16_as_ushort(__float2bfloat16(base[0]));
    uint b1 = (uint)__bfloat16_as_ushort(__float2bfloat16(base[HW_]));
    uint b2 = (uint)__bfloat16_as_ushort(__float2bfloat16(base[2 * HW_]));
    uvec2 v;
    v.x = b0 | (b1 << 16);
    v.y = b2;                 // hi16 = pad
    xi[idx] = v;

    if (blockIdx.x == 0) compute_theta(ksamp, rf, theta);
}

// ---------------- Stage 2: affine grid + bilinear sample, 1 px/thread ----------------
__global__ __launch_bounds__(256) void sample_kernel(const uvec2* __restrict__ xi,
                                                     const float* __restrict__ theta,
                                                     float* __restrict__ out) {
    int blk = blockIdx.x;
    int b   = blk / BLOCKS_PER_IMG;                    // uniform per block
    int pix = (blk % BLOCKS_PER_IMG) * 256 + threadIdx.x;
    int h = pix / W_, w = pix - h * W_;
    int n = b / S_;

    const float* th = theta + b * 6;
    float t00 = th[0], t01 = th[1], t02 = th[2];
    float t10 = th[3], t11 = th[4], t12 = th[5];

    float gx = fmaf((float)w, 2.f / (W_ - 1), -1.f);
    float gy = fmaf((float)h, 2.f / (H_ - 1), -1.f);

    float gridx = t00 * gx + t01 * gy + t02;
    float gridy = t10 * gx + t11 * gy + t12;

    float ix = (gridx + 1.f) * (0.5f * (W_ - 1));
    float iy = (gridy + 1.f) * (0.5f * (H_ - 1));

    float x0f = floorf(ix), y0f = floorf(iy);
    float wx1 = ix - x0f, wx0 = 1.f - wx1;
    float wy1 = iy - y0f, wy0 = 1.f - wy1;

    int x0 = (int)x0f, y0 = (int)y0f;
    int x1 = x0 + 1,   y1 = y0 + 1;

    bool vx0 = (x0 >= 0) && (x0 <= W_ - 1);
    bool vx1 = (x1 >= 0) && (x1 <= W_ - 1);
    bool vy0 = (y0 >= 0) && (y0 <= H_ - 1);
    bool vy1 = (y1 >= 0) && (y1 <= H_ - 1);

    float w00 = (vy0 && vx0) ? wy0 * wx0 : 0.f;
    float w01 = (vy0 && vx1) ? wy0 * wx1 : 0.f;
    float w10 = (vy1 && vx0) ? wy1 * wx0 : 0.f;
    float w11 = (vy1 && vx1) ? wy1 * wx1 : 0.f;

    int x0c = min(max(x0, 0), W_ - 1), x1c = min(max(x1, 0), W_ - 1);
    int y0c = min(max(y0, 0), H_ - 1), y1c = min(max(y1, 0), H_ - 1);

    const uvec2* img = xi + n * HW_;
    // pair loads: pixels (x0c, x0c+1) in rows y0c and y1c -- 16 contiguous B
    uvec4 r0, r1;
    __builtin_memcpy(&r0, img + (y0c * W_ + x0c), 16);
    __builtin_memcpy(&r1, img + (y1c * W_ + x0c), 16);

    bool cx = (x1c > x0c);  // hi pixel of the pair is x1c? (else both clamped)
    uint s0 = cx ? r0.z : r0.x;   // p01 channels (c0,c1)
    uint s1 = cx ? r0.w : r0.y;   // p01 channel c2
    uint t0 = cx ? r1.z : r1.x;   // p11 channels (c0,c1)
    uint t1 = cx ? r1.w : r1.y;   // p11 channel c2

    float vx = w00 * bflo(r0.x) + w01 * bflo(s0) + w10 * bflo(r1.x) + w11 * bflo(t0);
    float vy = w00 * bfhi(r0.x) + w01 * bfhi(s0) + w10 * bfhi(r1.x) + w11 * bfhi(t0);
    float vz = w00 * bflo(r0.y) + w01 * bflo(s1) + w10 * bflo(r1.y) + w11 * bflo(t1);

    float* ob = out + (size_t)b * (C_ * HW_) + pix;
    __builtin_nontemporal_store(vx, ob);
    __builtin_nontemporal_store(vy, ob + HW_);
    __builtin_nontemporal_store(vz, ob + 2 * (size_t)HW_);
}

extern "C" void kernel_launch(void* const* d_in, const int* in_sizes, int n_in,
                              void* d_out, int out_size, void* d_ws, size_t ws_size,
                              hipStream_t stream) {
    const float* x     = (const float*)d_in[0];
    const float* ksamp = (const float*)d_in[1];
    const float* rf    = (const float*)d_in[2];
    float* out   = (float*)d_out;
    float* theta = (float*)((char*)d_ws + THETA_OFF);
    uvec2* xi    = (uvec2*)((char*)d_ws + XI_OFF);

    prep_kernel<<<N_ * BLOCKS_PER_IMG, 256, 0, stream>>>(x, ksamp, rf, xi, theta);
    sample_kernel<<<B_ * BLOCKS_PER_IMG, 256, 0, stream>>>(xi, theta, out);
}